// Round 1
// baseline (205.703 us; speedup 1.0000x reference)
//
#include <hip/hip_runtime.h>
#include <hip/hip_bf16.h>

#define N_S    64
#define C_CH   128
#define L_SEQ  1600
#define H_HEADS 8
#define HD     16
#define SEG    50   // 32 segments * 50 = 1600

// ---------------- K0: transpose Wa, Wp (128x128 each) ----------------
__global__ __launch_bounds__(256) void k_transpose(const float* __restrict__ Wa,
                                                   const float* __restrict__ Wp,
                                                   float* __restrict__ waT,
                                                   float* __restrict__ wpT) {
  int b = blockIdx.x;
  int idx = (b & 63) * 256 + threadIdx.x;   // 0..16383
  int o = idx >> 7, c = idx & 127;
  if (b < 64) waT[c * 128 + o] = Wa[idx];
  else        wpT[c * 128 + o] = Wp[idx];
}

// ---------------- K1: w[n,h,l,d] = sum_c x[n,c,l] * Wa[o=16h+d][c] + ba[o] ----------------
__global__ __launch_bounds__(256) void k_gemm1(const float* __restrict__ x,
                                               const float* __restrict__ waT,
                                               const float* __restrict__ ba,
                                               float* __restrict__ w) {
  __shared__ float xs[128][64];
  const int n = blockIdx.y;
  const int l0 = blockIdx.x * 64;
  const float* xn = x + (size_t)n * (C_CH * L_SEQ);
  const int t = threadIdx.x;
  // stage x tile: 128 c x 64 l (2048 float4, 8 per thread), coalesced
#pragma unroll
  for (int it = 0; it < 8; ++it) {
    int idx = it * 256 + t;
    int c = idx >> 4;
    int l4 = (idx & 15) << 2;
    float4 v = *reinterpret_cast<const float4*>(xn + c * L_SEQ + l0 + l4);
    *reinterpret_cast<float4*>(&xs[c][l4]) = v;
  }
  __syncthreads();
  const int l = t & 63;
  const int og = __builtin_amdgcn_readfirstlane(t >> 6);  // wave-uniform o-group
  float acc[32];
#pragma unroll
  for (int j = 0; j < 32; ++j) acc[j] = 0.f;
  const float* wbase = waT + og * 32;
#pragma unroll 2
  for (int c = 0; c < 128; ++c) {
    float xv = xs[c][l];
    const float* wrow = wbase + c * 128;   // wave-uniform, contiguous -> s_load
#pragma unroll
    for (int j = 0; j < 32; ++j) acc[j] += wrow[j] * xv;
  }
  const int gl = l0 + l;
#pragma unroll
  for (int j = 0; j < 32; ++j) {
    int o = og * 32 + j;
    int hh = o >> 4, dd = o & 15;
    w[(((size_t)n * H_HEADS + hh) * L_SEQ + gl) * HD + dd] = acc[j] + ba[o];
  }
}

// ---------------- K2: per-(n,h) scan pipeline; y overwrites w in place ----------------
__global__ __launch_bounds__(512) void k_scan(float* __restrict__ w,
                                              const float* __restrict__ temp,
                                              const float* __restrict__ dbias) {
  __shared__ float tmp_l[L_SEQ];     // tmp, then e = exp(tmp - M)
  __shared__ float stot[32][17];     // per-segment totals (padded)
  __shared__ float pi_seg[32];
  __shared__ float red[16];
  const int nh = blockIdx.x;         // n*8 + h
  const int h = nh & 7;
  float* base = w + (size_t)nh * (L_SEQ * HD);
  const int t = threadIdx.x;
  const int d = t & 15;
  const int seg = t >> 4;
  const int l0 = seg * SEG;
  float* p = base + l0 * HD + d;
  const float tscale = temp[h];
  const float db16 = 16.f * dbias[h];

  // ---- sweep 1a: per-segment sum of w^2 (per channel d) ----
  float tot = 0.f;
#pragma unroll 5
  for (int i = 0; i < SEG; ++i) { float v = p[i * HD]; tot += v * v; }
  stot[seg][d] = tot;
  __syncthreads();
  float off = 0.f;
#pragma unroll
  for (int s = 0; s < 32; ++s) { float v = stot[s][d]; if (s < seg) off += v; }

  // ---- sweep 1b: inclusive cumsum -> tmp[l] = (sum_d wsq/denom + 16*db)*temp ----
  {
    float run = off;
#pragma unroll 5
    for (int i = 0; i < SEG; ++i) {
      float v = p[i * HD];
      float wsq = v * v;
      run += wsq;
      float dn = fmaxf(run, 1e-12f);
      float c0 = __fdividef(wsq, dn);
      c0 += __shfl_xor(c0, 1);
      c0 += __shfl_xor(c0, 2);
      c0 += __shfl_xor(c0, 4);
      c0 += __shfl_xor(c0, 8);
      if (d == 0) tmp_l[l0 + i] = (c0 + db16) * tscale;
    }
  }
  __syncthreads();

  // ---- softmax over tmp_l[0..1599] ----
  float m = -3.0e38f;
  for (int l = t; l < L_SEQ; l += 512) m = fmaxf(m, tmp_l[l]);
#pragma unroll
  for (int mask = 32; mask; mask >>= 1) m = fmaxf(m, __shfl_xor(m, mask));
  const int wid = t >> 6;
  if ((t & 63) == 0) red[wid] = m;
  __syncthreads();
  float M = red[0];
#pragma unroll
  for (int i2 = 1; i2 < 8; ++i2) M = fmaxf(M, red[i2]);
  float s = 0.f;
  for (int l = t; l < L_SEQ; l += 512) {
    float e = __expf(tmp_l[l] - M);
    tmp_l[l] = e;
    s += e;
  }
#pragma unroll
  for (int mask = 32; mask; mask >>= 1) s += __shfl_xor(s, mask);
  if ((t & 63) == 0) red[8 + wid] = s;
  __syncthreads();
  float S = 0.f;
#pragma unroll
  for (int i2 = 0; i2 < 8; ++i2) S += red[8 + i2];
  const float invS = 1.0f / S;   // Pi[l] = tmp_l[l] * invS

  // ---- sweep 2a: per-segment totals of wsq*Pi (per d) and Pi ----
  float wp_tot = 0.f, pi_tot = 0.f;
#pragma unroll 5
  for (int i = 0; i < SEG; ++i) {
    float v = p[i * HD];
    float pi = tmp_l[l0 + i] * invS;
    wp_tot += v * v * pi;
    pi_tot += pi;
  }
  stot[seg][d] = wp_tot;
  if (d == 0) pi_seg[seg] = pi_tot;
  __syncthreads();
  float wp_off = 0.f, pi_off = 0.f;
#pragma unroll
  for (int s2 = 0; s2 < 32; ++s2) {
    float vw = stot[s2][d];
    float vp = pi_seg[s2];
    if (s2 < seg) { wp_off += vw; pi_off += vp; }
  }

  // ---- sweep 2b: running cumsums -> y = -(w*Pi) * (cpi+1e-8)/((cpi+1e-8)+cwp) ----
  {
    float run_wp = wp_off, run_pi = pi_off;
#pragma unroll 5
    for (int i = 0; i < SEG; ++i) {
      float v = p[i * HD];
      float pi = tmp_l[l0 + i] * invS;
      run_pi += pi;
      float wsq = v * v;
      run_wp += wsq * pi;
      float dn = run_pi + 1e-8f;
      float attn = __fdividef(dn, dn + run_wp);
      p[i * HD] = -(v * pi) * attn;
    }
  }
}

// ---------------- K3: out[n,o,l] = relu(sum_c Wp[o][c]*y[n,c,l] + bp[o] + x[n,o,l]) ----------------
__global__ __launch_bounds__(256) void k_gemm2(const float* __restrict__ y,
                                               const float* __restrict__ wpT,
                                               const float* __restrict__ bp,
                                               const float* __restrict__ x,
                                               float* __restrict__ out) {
  __shared__ float ys[128][64];
  const int n = blockIdx.y;
  const int l0 = blockIdx.x * 64;
  const float* yn = y + (size_t)n * (H_HEADS * L_SEQ * HD);
  const int t = threadIdx.x;
  // stage y tile with transpose: y[h][l][d] -> ys[c=16h+d][l]
#pragma unroll
  for (int hh = 0; hh < H_HEADS; ++hh) {
    int l = t >> 2;
    int d4 = (t & 3) << 2;
    float4 v = *reinterpret_cast<const float4*>(yn + (size_t)hh * (L_SEQ * HD) + (size_t)(l0 + l) * HD + d4);
    ys[hh * 16 + d4 + 0][l] = v.x;
    ys[hh * 16 + d4 + 1][l] = v.y;
    ys[hh * 16 + d4 + 2][l] = v.z;
    ys[hh * 16 + d4 + 3][l] = v.w;
  }
  __syncthreads();
  const int l = t & 63;
  const int og = __builtin_amdgcn_readfirstlane(t >> 6);
  float acc[32];
#pragma unroll
  for (int j = 0; j < 32; ++j) acc[j] = 0.f;
  const float* wbase = wpT + og * 32;
#pragma unroll 2
  for (int c = 0; c < 128; ++c) {
    float yv = ys[c][l];
    const float* wrow = wbase + c * 128;
#pragma unroll
    for (int j = 0; j < 32; ++j) acc[j] += wrow[j] * yv;
  }
  const int gl = l0 + l;
  const size_t obase = (size_t)n * (C_CH * L_SEQ) + gl;
#pragma unroll
  for (int j = 0; j < 32; ++j) {
    int o = og * 32 + j;
    float r = acc[j] + bp[o] + x[obase + (size_t)o * L_SEQ];
    out[obase + (size_t)o * L_SEQ] = fmaxf(r, 0.f);
  }
}

extern "C" void kernel_launch(void* const* d_in, const int* in_sizes, int n_in,
                              void* d_out, int out_size, void* d_ws, size_t ws_size,
                              hipStream_t stream) {
  const float* x     = (const float*)d_in[0];
  const float* Wa    = (const float*)d_in[1];
  const float* ba    = (const float*)d_in[2];
  const float* Wp    = (const float*)d_in[3];
  const float* bp    = (const float*)d_in[4];
  const float* temp  = (const float*)d_in[5];
  const float* dbias = (const float*)d_in[6];
  float* out = (float*)d_out;

  float* w   = (float*)d_ws;                                   // 13,107,200 floats (52.4 MB)
  float* waT = w + (size_t)N_S * H_HEADS * L_SEQ * HD;
  float* wpT = waT + 128 * 128;

  k_transpose<<<128, 256, 0, stream>>>(Wa, Wp, waT, wpT);
  k_gemm1<<<dim3(L_SEQ / 64, N_S), 256, 0, stream>>>(x, waT, ba, w);
  k_scan<<<N_S * H_HEADS, 512, 0, stream>>>(w, temp, dbias);
  k_gemm2<<<dim3(L_SEQ / 64, N_S), 256, 0, stream>>>(w, wpT, bp, x, out);
}

// Round 2
// 94.368 us; speedup vs baseline: 2.1798x; 2.1798x over previous
//
#include <hip/hip_runtime.h>
#include <hip/hip_bf16.h>

#define N_S     64
#define C_CH    128
#define L_SEQ   1600
#define H_HEADS 8
#define HD      16
#define SEG     50    // 32 segments * 50 = 1600
#define PADC    136   // padded row length in bf16 elems (272B, multiple of 16B)

typedef __attribute__((ext_vector_type(8))) short bf16x8;
typedef __attribute__((ext_vector_type(4))) float f32x4;

__device__ inline unsigned short f2bf(float f) {
  return __builtin_bit_cast(unsigned short, __float2bfloat16(f));
}

// ---------------- K1: w[n,h,l,d] = sum_c x[n,c,l]*Wa[16h+d][c] + ba  (bf16 MFMA) ----------------
// D[l-tile][o-tile]: A = x^T (l x c), B = Wa^T-as-B (lane reads Wa[o][c..c+7])
__global__ __launch_bounds__(256) void k_gemm1(const float* __restrict__ x,
                                               const float* __restrict__ Wa,
                                               const float* __restrict__ ba,
                                               float* __restrict__ w) {
  __shared__ unsigned short xs[64 * PADC];     // [l][c]
  __shared__ unsigned short was[128 * PADC];   // [o][c]
  const int n = blockIdx.y;
  const int l0 = blockIdx.x * 64;
  const int t = threadIdx.x;
  const float* xn = x + (size_t)n * (C_CH * L_SEQ);

  // stage Wa (fp32 -> bf16), coalesced float4 reads, 8B LDS writes
#pragma unroll
  for (int it = 0; it < 16; ++it) {
    int pos = it * 256 + t;
    int o = pos >> 5;
    int c4 = (pos & 31) << 2;
    float4 v = *reinterpret_cast<const float4*>(Wa + o * C_CH + c4);
    ushort4 u;
    u.x = f2bf(v.x); u.y = f2bf(v.y); u.z = f2bf(v.z); u.w = f2bf(v.w);
    *reinterpret_cast<ushort4*>(&was[o * PADC + c4]) = u;
  }
  // stage x^T tile: 4 coalesced dword reads per thread, contiguous 8B LDS write
#pragma unroll
  for (int it = 0; it < 8; ++it) {
    int pos = it * 256 + t;
    int l = pos & 63;
    int c4 = (pos >> 6) << 2;
    const float* src = xn + (size_t)c4 * L_SEQ + l0 + l;
    ushort4 u;
    u.x = f2bf(src[0]);
    u.y = f2bf(src[L_SEQ]);
    u.z = f2bf(src[2 * L_SEQ]);
    u.w = f2bf(src[3 * L_SEQ]);
    *reinterpret_cast<ushort4*>(&xs[l * PADC + c4]) = u;
  }
  __syncthreads();

  const int wv = t >> 6;        // wave -> l sub-tile
  const int lane = t & 63;
  const int r16 = lane & 15;
  const int kg = lane >> 4;
  f32x4 acc[8];
#pragma unroll
  for (int ot = 0; ot < 8; ++ot) acc[ot] = (f32x4){0.f, 0.f, 0.f, 0.f};

#pragma unroll
  for (int ks = 0; ks < 4; ++ks) {
    bf16x8 a = *reinterpret_cast<const bf16x8*>(&xs[(wv * 16 + r16) * PADC + ks * 32 + kg * 8]);
#pragma unroll
    for (int ot = 0; ot < 8; ++ot) {
      bf16x8 b = *reinterpret_cast<const bf16x8*>(&was[(ot * 16 + r16) * PADC + ks * 32 + kg * 8]);
      acc[ot] = __builtin_amdgcn_mfma_f32_16x16x32_bf16(a, b, acc[ot], 0, 0, 0);
    }
  }
  // C layout: col (=d) = lane&15, row (=l-local) = kg*4 + i ; o-tile == head
#pragma unroll
  for (int ot = 0; ot < 8; ++ot) {
    float bav = ba[ot * 16 + r16];
    size_t base = (((size_t)n * H_HEADS + ot) * L_SEQ + (l0 + wv * 16 + kg * 4)) * HD + r16;
#pragma unroll
    for (int i = 0; i < 4; ++i)
      w[base + (size_t)i * HD] = acc[ot][i] + bav;
  }
}

// ---------------- K2: per-(n,h) scan pipeline, register-resident slice ----------------
__global__ __launch_bounds__(512) void k_scan(float* __restrict__ w,
                                              const float* __restrict__ temp,
                                              const float* __restrict__ dbias) {
  __shared__ float tmp_l[L_SEQ];
  __shared__ float stot[32][17];
  __shared__ float pi_seg[32];
  __shared__ float red[16];
  const int nh = blockIdx.x;
  const int h = nh & 7;
  const int t = threadIdx.x;
  const int d = t & 15;
  const int seg = t >> 4;
  const int l0 = seg * SEG;
  float* p = w + (size_t)nh * (L_SEQ * HD) + (size_t)l0 * HD + d;
  const float tscale = temp[h];
  const float db16 = 16.f * dbias[h];

  // load this thread's 50-element slice into registers (only global read)
  float v[SEG];
#pragma unroll
  for (int i = 0; i < SEG; ++i) v[i] = p[i * HD];

  // sweep 1a: per-segment sum of w^2 per channel
  float tot = 0.f;
#pragma unroll
  for (int i = 0; i < SEG; ++i) tot += v[i] * v[i];
  stot[seg][d] = tot;
  __syncthreads();
  float off = 0.f;
#pragma unroll
  for (int s = 0; s < 32; ++s) { float q = stot[s][d]; if (s < seg) off += q; }

  // sweep 1b: cumsum -> tmp[l]
  {
    float run = off;
#pragma unroll
    for (int i = 0; i < SEG; ++i) {
      float wsq = v[i] * v[i];
      run += wsq;
      float c0 = __fdividef(wsq, fmaxf(run, 1e-12f));
      c0 += __shfl_xor(c0, 1);
      c0 += __shfl_xor(c0, 2);
      c0 += __shfl_xor(c0, 4);
      c0 += __shfl_xor(c0, 8);
      if (d == 0) tmp_l[l0 + i] = (c0 + db16) * tscale;
    }
  }
  __syncthreads();

  // softmax over tmp_l[0..1599]
  float m = -3.0e38f;
  for (int l = t; l < L_SEQ; l += 512) m = fmaxf(m, tmp_l[l]);
#pragma unroll
  for (int mask = 32; mask; mask >>= 1) m = fmaxf(m, __shfl_xor(m, mask));
  const int wid = t >> 6;
  if ((t & 63) == 0) red[wid] = m;
  __syncthreads();
  float M = red[0];
#pragma unroll
  for (int i2 = 1; i2 < 8; ++i2) M = fmaxf(M, red[i2]);
  float s = 0.f;
  for (int l = t; l < L_SEQ; l += 512) {
    float e = __expf(tmp_l[l] - M);
    tmp_l[l] = e;
    s += e;
  }
#pragma unroll
  for (int mask = 32; mask; mask >>= 1) s += __shfl_xor(s, mask);
  if ((t & 63) == 0) red[8 + wid] = s;
  __syncthreads();
  float S = 0.f;
#pragma unroll
  for (int i2 = 0; i2 < 8; ++i2) S += red[8 + i2];
  const float invS = 1.0f / S;

  // sweep 2a: per-segment totals of wsq*Pi (per d) and Pi
  float wp_tot = 0.f, pi_tot = 0.f;
#pragma unroll
  for (int i = 0; i < SEG; ++i) {
    float pi = tmp_l[l0 + i] * invS;
    wp_tot += v[i] * v[i] * pi;
    pi_tot += pi;
  }
  stot[seg][d] = wp_tot;
  if (d == 0) pi_seg[seg] = pi_tot;
  __syncthreads();
  float wp_off = 0.f, pi_off = 0.f;
#pragma unroll
  for (int s2 = 0; s2 < 32; ++s2) {
    float vw = stot[s2][d];
    float vp = pi_seg[s2];
    if (s2 < seg) { wp_off += vw; pi_off += vp; }
  }

  // sweep 2b: running cumsums -> y (in place)
  {
    float run_wp = wp_off, run_pi = pi_off;
#pragma unroll
    for (int i = 0; i < SEG; ++i) {
      float pi = tmp_l[l0 + i] * invS;
      run_pi += pi;
      float wsq = v[i] * v[i];
      run_wp += wsq * pi;
      float dn = run_pi + 1e-8f;
      float attn = __fdividef(dn, dn + run_wp);
      p[i * HD] = -(v[i] * pi) * attn;
    }
  }
}

// ---------------- K3: out = relu(Wp . y + bp + x)  (bf16 MFMA) ----------------
// D[o-tile][l-tile]: A = Wp (o x c), B = y^T (c x l)
__global__ __launch_bounds__(256) void k_gemm2(const float* __restrict__ y,
                                               const float* __restrict__ Wp,
                                               const float* __restrict__ bp,
                                               const float* __restrict__ x,
                                               float* __restrict__ out) {
  __shared__ unsigned short ys[64 * PADC];     // [l][c]
  __shared__ unsigned short wps[128 * PADC];   // [o][c]
  const int n = blockIdx.y;
  const int l0 = blockIdx.x * 64;
  const int t = threadIdx.x;
  const float* yn = y + (size_t)n * (H_HEADS * L_SEQ * HD);

#pragma unroll
  for (int it = 0; it < 16; ++it) {
    int pos = it * 256 + t;
    int o = pos >> 5;
    int c4 = (pos & 31) << 2;
    float4 v = *reinterpret_cast<const float4*>(Wp + o * C_CH + c4);
    ushort4 u;
    u.x = f2bf(v.x); u.y = f2bf(v.y); u.z = f2bf(v.z); u.w = f2bf(v.w);
    *reinterpret_cast<ushort4*>(&wps[o * PADC + c4]) = u;
  }
  // stage y -> ys[l][c] where c = 16h+d (float4 over d)
#pragma unroll
  for (int it = 0; it < 8; ++it) {
    int pos = it * 256 + t;
    int l = pos & 63;
    int cg = pos >> 6;          // 0..31, c = cg*4
    int hh = cg >> 2;
    int d4 = (cg & 3) << 2;
    float4 v = *reinterpret_cast<const float4*>(yn + ((size_t)hh * L_SEQ + l0 + l) * HD + d4);
    ushort4 u;
    u.x = f2bf(v.x); u.y = f2bf(v.y); u.z = f2bf(v.z); u.w = f2bf(v.w);
    *reinterpret_cast<ushort4*>(&ys[l * PADC + (cg << 2)]) = u;
  }
  __syncthreads();

  const int wv = t >> 6;        // wave -> l sub-tile
  const int lane = t & 63;
  const int r16 = lane & 15;
  const int kg = lane >> 4;
  f32x4 acc[8];
#pragma unroll
  for (int ot = 0; ot < 8; ++ot) acc[ot] = (f32x4){0.f, 0.f, 0.f, 0.f};

#pragma unroll
  for (int ks = 0; ks < 4; ++ks) {
    bf16x8 b = *reinterpret_cast<const bf16x8*>(&ys[(wv * 16 + r16) * PADC + ks * 32 + kg * 8]);
#pragma unroll
    for (int ot = 0; ot < 8; ++ot) {
      bf16x8 a = *reinterpret_cast<const bf16x8*>(&wps[(ot * 16 + r16) * PADC + ks * 32 + kg * 8]);
      acc[ot] = __builtin_amdgcn_mfma_f32_16x16x32_bf16(a, b, acc[ot], 0, 0, 0);
    }
  }
  // C layout: col (=l-local) = lane&15, row (=o-local) = kg*4 + i
  const int gl = l0 + wv * 16 + r16;
#pragma unroll
  for (int ot = 0; ot < 8; ++ot) {
#pragma unroll
    for (int i = 0; i < 4; ++i) {
      int o = ot * 16 + kg * 4 + i;
      size_t idx = (size_t)n * (C_CH * L_SEQ) + (size_t)o * L_SEQ + gl;
      float r = acc[ot][i] + bp[o] + x[idx];
      out[idx] = fmaxf(r, 0.f);
    }
  }
}

extern "C" void kernel_launch(void* const* d_in, const int* in_sizes, int n_in,
                              void* d_out, int out_size, void* d_ws, size_t ws_size,
                              hipStream_t stream) {
  const float* x     = (const float*)d_in[0];
  const float* Wa    = (const float*)d_in[1];
  const float* ba    = (const float*)d_in[2];
  const float* Wp    = (const float*)d_in[3];
  const float* bp    = (const float*)d_in[4];
  const float* temp  = (const float*)d_in[5];
  const float* dbias = (const float*)d_in[6];
  float* out = (float*)d_out;

  float* w = (float*)d_ws;   // 64*8*1600*16 floats = 52.4 MB

  k_gemm1<<<dim3(L_SEQ / 64, N_S), 256, 0, stream>>>(x, Wa, ba, w);
  k_scan<<<N_S * H_HEADS, 512, 0, stream>>>(w, temp, dbias);
  k_gemm2<<<dim3(L_SEQ / 64, N_S), 256, 0, stream>>>(w, Wp, bp, x, out);
}

// Round 3
// 89.870 us; speedup vs baseline: 2.2889x; 1.0501x over previous
//
#include <hip/hip_runtime.h>
#include <hip/hip_bf16.h>

#define N_S     64
#define C_CH    128
#define L_SEQ   1600
#define H_HEADS 8
#define HD      16
#define SEG     50    // 32 segments * 50 = 1600
#define PADW    136   // weight LDS row pad (bf16 elems)
#define PADT    72    // x/y tile LDS row pad (bf16 elems)

typedef __attribute__((ext_vector_type(8))) short bf16x8;
typedef __attribute__((ext_vector_type(4))) float f32x4;

__device__ inline unsigned short f2bf(float f) {
  return __builtin_bit_cast(unsigned short, __float2bfloat16(f));
}
__device__ inline float bflo(unsigned int u) { return __builtin_bit_cast(float, u << 16); }
__device__ inline float bfhi(unsigned int u) { return __builtin_bit_cast(float, u & 0xffff0000u); }

// ---------------- K1: w2[n, c=16h+d, l] (bf16) = sum_c x[n,c,l]*Wa[16h+d][c] + ba ----------------
__global__ __launch_bounds__(256) void k_gemm1(const float* __restrict__ x,
                                               const float* __restrict__ Wa,
                                               const float* __restrict__ ba,
                                               unsigned short* __restrict__ w2) {
  __shared__ unsigned short was[128 * PADW];   // [o][c] rows
  __shared__ unsigned short xs[128 * PADT];    // [c][l] natural layout
  const int n = blockIdx.y;
  const int l0 = blockIdx.x * 64;
  const int t = threadIdx.x;
  const float* xn = x + (size_t)n * (C_CH * L_SEQ);

  // stage Wa fp32->bf16 (coalesced float4 reads, 8B LDS writes)
#pragma unroll
  for (int it = 0; it < 16; ++it) {
    int pos = it * 256 + t;
    int o = pos >> 5;
    int c4 = (pos & 31) << 2;
    float4 v = *reinterpret_cast<const float4*>(Wa + o * C_CH + c4);
    ushort4 u;
    u.x = f2bf(v.x); u.y = f2bf(v.y); u.z = f2bf(v.z); u.w = f2bf(v.w);
    *reinterpret_cast<ushort4*>(&was[o * PADW + c4]) = u;
  }
  // stage x tile [c][l] directly (no transpose)
#pragma unroll
  for (int it = 0; it < 8; ++it) {
    int pos = it * 256 + t;
    int c = pos >> 4;
    int l4 = (pos & 15) << 2;
    float4 v = *reinterpret_cast<const float4*>(xn + (size_t)c * L_SEQ + l0 + l4);
    ushort4 u;
    u.x = f2bf(v.x); u.y = f2bf(v.y); u.z = f2bf(v.z); u.w = f2bf(v.w);
    *reinterpret_cast<ushort4*>(&xs[c * PADT + l4]) = u;
  }
  __syncthreads();

  const int wv = t >> 6;
  const int lane = t & 63;
  const int r16 = lane & 15;
  const int kg = lane >> 4;
  f32x4 acc[8];
#pragma unroll
  for (int ot = 0; ot < 8; ++ot) acc[ot] = (f32x4){0.f, 0.f, 0.f, 0.f};

#pragma unroll
  for (int ks = 0; ks < 4; ++ks) {
    bf16x8 a;
#pragma unroll
    for (int j = 0; j < 8; ++j)
      a[j] = (short)xs[(ks * 32 + kg * 8 + j) * PADT + wv * 16 + r16];
#pragma unroll
    for (int ot = 0; ot < 8; ++ot) {
      bf16x8 b = *reinterpret_cast<const bf16x8*>(&was[(ot * 16 + r16) * PADW + ks * 32 + kg * 8]);
      acc[ot] = __builtin_amdgcn_mfma_f32_16x16x32_bf16(a, b, acc[ot], 0, 0, 0);
    }
  }
  // D[row=l-local][col=d]; lane holds 4 consecutive l at fixed d -> ushort4 store
#pragma unroll
  for (int ot = 0; ot < 8; ++ot) {
    float bav = ba[ot * 16 + r16];
    ushort4 u;
    u.x = f2bf(acc[ot][0] + bav);
    u.y = f2bf(acc[ot][1] + bav);
    u.z = f2bf(acc[ot][2] + bav);
    u.w = f2bf(acc[ot][3] + bav);
    size_t idx = (((size_t)n * H_HEADS + ot) * HD + r16) * L_SEQ + l0 + wv * 16 + kg * 4;
    *reinterpret_cast<ushort4*>(&w2[idx]) = u;
  }
}

// ---------------- K2: per-(n,h) scan pipeline; bf16 in/out, register-resident packed ----------------
__global__ __launch_bounds__(512) void k_scan(const unsigned short* __restrict__ w2,
                                              unsigned short* __restrict__ y2,
                                              const float* __restrict__ temp,
                                              const float* __restrict__ dbias) {
  __shared__ float tmp_l[L_SEQ];
  __shared__ float stot[32][17];
  __shared__ float pi_seg[32];
  __shared__ float red[16];
  const int nh = blockIdx.x;
  const int h = nh & 7;
  const int t = threadIdx.x;
  const int d = t & 15;
  const int seg = t >> 4;
  const int l0 = seg * SEG;
  const size_t base = ((size_t)nh * HD + d) * L_SEQ + l0;
  const float tscale = temp[h];
  const float db16 = 16.f * dbias[h];

  // contiguous 50-elem bf16 slice -> 25 packed dwords
  unsigned int vp[25];
#pragma unroll
  for (int ii = 0; ii < 25; ++ii)
    vp[ii] = *reinterpret_cast<const unsigned int*>(w2 + base + 2 * ii);

  // sweep 1a: per-segment sum of w^2 per channel
  float tot = 0.f;
#pragma unroll
  for (int ii = 0; ii < 25; ++ii) {
    float a = bflo(vp[ii]), b = bfhi(vp[ii]);
    tot += a * a + b * b;
  }
  stot[seg][d] = tot;
  __syncthreads();
  float off = 0.f;
#pragma unroll
  for (int s = 0; s < 32; ++s) { float q = stot[s][d]; if (s < seg) off += q; }

  // sweep 1b: cumsum -> tmp[l]; tiles of 10 independent shfl chains
  {
    float run = off;
#pragma unroll
    for (int i0 = 0; i0 < SEG; i0 += 10) {
      float c0[10];
#pragma unroll
      for (int j = 0; j < 10; ++j) {
        int i = i0 + j;
        float v = (i & 1) ? bfhi(vp[i >> 1]) : bflo(vp[i >> 1]);
        float wsq = v * v;
        run += wsq;
        c0[j] = __fdividef(wsq, fmaxf(run, 1e-12f));
      }
#pragma unroll
      for (int j = 0; j < 10; ++j) {
        float c = c0[j];
        c += __shfl_xor(c, 1);
        c += __shfl_xor(c, 2);
        c += __shfl_xor(c, 4);
        c += __shfl_xor(c, 8);
        if (d == 0) tmp_l[l0 + i0 + j] = (c + db16) * tscale;
      }
    }
  }
  __syncthreads();

  // softmax over tmp_l[0..1599]
  float m = -3.0e38f;
  for (int l = t; l < L_SEQ; l += 512) m = fmaxf(m, tmp_l[l]);
#pragma unroll
  for (int mask = 32; mask; mask >>= 1) m = fmaxf(m, __shfl_xor(m, mask));
  const int wid = t >> 6;
  if ((t & 63) == 0) red[wid] = m;
  __syncthreads();
  float M = red[0];
#pragma unroll
  for (int i2 = 1; i2 < 8; ++i2) M = fmaxf(M, red[i2]);
  float s = 0.f;
  for (int l = t; l < L_SEQ; l += 512) {
    float e = __expf(tmp_l[l] - M);
    tmp_l[l] = e;
    s += e;
  }
#pragma unroll
  for (int mask = 32; mask; mask >>= 1) s += __shfl_xor(s, mask);
  if ((t & 63) == 0) red[8 + wid] = s;
  __syncthreads();
  float S = 0.f;
#pragma unroll
  for (int i2 = 0; i2 < 8; ++i2) S += red[8 + i2];
  const float invS = 1.0f / S;

  // sweep 2a: per-segment totals of wsq*Pi (per d) and Pi
  float wp_tot = 0.f, pi_tot = 0.f;
#pragma unroll
  for (int ii = 0; ii < 25; ++ii) {
    float a = bflo(vp[ii]), b = bfhi(vp[ii]);
    float pi0 = tmp_l[l0 + 2 * ii] * invS;
    float pi1 = tmp_l[l0 + 2 * ii + 1] * invS;
    wp_tot += a * a * pi0 + b * b * pi1;
    pi_tot += pi0 + pi1;
  }
  stot[seg][d] = wp_tot;
  if (d == 0) pi_seg[seg] = pi_tot;
  __syncthreads();
  float wp_off = 0.f, pi_off = 0.f;
#pragma unroll
  for (int s2 = 0; s2 < 32; ++s2) {
    float vw = stot[s2][d];
    float vq = pi_seg[s2];
    if (s2 < seg) { wp_off += vw; pi_off += vq; }
  }

  // sweep 2b: running cumsums -> y packed into vp, then contiguous stores
  {
    float run_wp = wp_off, run_pi = pi_off;
#pragma unroll
    for (int ii = 0; ii < 25; ++ii) {
      float v0 = bflo(vp[ii]), v1 = bfhi(vp[ii]);
      float pi0 = tmp_l[l0 + 2 * ii] * invS;
      run_pi += pi0;
      run_wp += v0 * v0 * pi0;
      float dn0 = run_pi + 1e-8f;
      float y0 = -(v0 * pi0) * __fdividef(dn0, dn0 + run_wp);
      float pi1 = tmp_l[l0 + 2 * ii + 1] * invS;
      run_pi += pi1;
      run_wp += v1 * v1 * pi1;
      float dn1 = run_pi + 1e-8f;
      float y1 = -(v1 * pi1) * __fdividef(dn1, dn1 + run_wp);
      vp[ii] = (unsigned int)f2bf(y0) | ((unsigned int)f2bf(y1) << 16);
    }
  }
#pragma unroll
  for (int ii = 0; ii < 25; ++ii)
    *reinterpret_cast<unsigned int*>(y2 + base + 2 * ii) = vp[ii];
}

// ---------------- K3: out = relu(Wp . y + bp + x)  (bf16 MFMA, y2 d-major) ----------------
__global__ __launch_bounds__(256) void k_gemm2(const unsigned short* __restrict__ y2,
                                               const float* __restrict__ Wp,
                                               const float* __restrict__ bp,
                                               const float* __restrict__ x,
                                               float* __restrict__ out) {
  __shared__ unsigned short wps[128 * PADW];   // [o][c] rows
  __shared__ unsigned short ys[128 * PADT];    // [c][l] natural layout
  const int n = blockIdx.y;
  const int l0 = blockIdx.x * 64;
  const int t = threadIdx.x;

#pragma unroll
  for (int it = 0; it < 16; ++it) {
    int pos = it * 256 + t;
    int o = pos >> 5;
    int c4 = (pos & 31) << 2;
    float4 v = *reinterpret_cast<const float4*>(Wp + o * C_CH + c4);
    ushort4 u;
    u.x = f2bf(v.x); u.y = f2bf(v.y); u.z = f2bf(v.z); u.w = f2bf(v.w);
    *reinterpret_cast<ushort4*>(&wps[o * PADW + c4]) = u;
  }
  // stage y tile [c][l]: pure 16B copies, no conversion, no transpose
#pragma unroll
  for (int it = 0; it < 4; ++it) {
    int pos = it * 256 + t;          // 0..1023
    int c = pos >> 3;
    int l8 = (pos & 7) << 3;
    uint4 v = *reinterpret_cast<const uint4*>(y2 + ((size_t)n * C_CH + c) * L_SEQ + l0 + l8);
    *reinterpret_cast<uint4*>(&ys[c * PADT + l8]) = v;
  }
  __syncthreads();

  const int wv = t >> 6;
  const int lane = t & 63;
  const int r16 = lane & 15;
  const int kg = lane >> 4;
  f32x4 acc[8];
#pragma unroll
  for (int ot = 0; ot < 8; ++ot) acc[ot] = (f32x4){0.f, 0.f, 0.f, 0.f};

#pragma unroll
  for (int ks = 0; ks < 4; ++ks) {
    bf16x8 b;
#pragma unroll
    for (int j = 0; j < 8; ++j)
      b[j] = (short)ys[(ks * 32 + kg * 8 + j) * PADT + wv * 16 + r16];
#pragma unroll
    for (int ot = 0; ot < 8; ++ot) {
      bf16x8 a = *reinterpret_cast<const bf16x8*>(&wps[(ot * 16 + r16) * PADW + ks * 32 + kg * 8]);
      acc[ot] = __builtin_amdgcn_mfma_f32_16x16x32_bf16(a, b, acc[ot], 0, 0, 0);
    }
  }
  // D[row=o-local][col=l]; lanes r16 give 16 consecutive l -> coalesced fp32 stores
  const int gl = l0 + wv * 16 + r16;
#pragma unroll
  for (int ot = 0; ot < 8; ++ot) {
#pragma unroll
    for (int i = 0; i < 4; ++i) {
      int o = ot * 16 + kg * 4 + i;
      size_t idx = (size_t)n * (C_CH * L_SEQ) + (size_t)o * L_SEQ + gl;
      float r = acc[ot][i] + bp[o] + x[idx];
      out[idx] = fmaxf(r, 0.f);
    }
  }
}

extern "C" void kernel_launch(void* const* d_in, const int* in_sizes, int n_in,
                              void* d_out, int out_size, void* d_ws, size_t ws_size,
                              hipStream_t stream) {
  const float* x     = (const float*)d_in[0];
  const float* Wa    = (const float*)d_in[1];
  const float* ba    = (const float*)d_in[2];
  const float* Wp    = (const float*)d_in[3];
  const float* bp    = (const float*)d_in[4];
  const float* temp  = (const float*)d_in[5];
  const float* dbias = (const float*)d_in[6];
  float* out = (float*)d_out;

  unsigned short* w2 = (unsigned short*)d_ws;                       // 26.2 MB
  unsigned short* y2 = w2 + (size_t)N_S * H_HEADS * L_SEQ * HD;     // 26.2 MB

  k_gemm1<<<dim3(L_SEQ / 64, N_S), 256, 0, stream>>>(x, Wa, ba, w2);
  k_scan<<<N_S * H_HEADS, 512, 0, stream>>>(w2, y2, temp, dbias);
  k_gemm2<<<dim3(L_SEQ / 64, N_S), 256, 0, stream>>>(y2, Wp, bp, x, out);
}

// Round 4
// 79.715 us; speedup vs baseline: 2.5805x; 1.1274x over previous
//
#include <hip/hip_runtime.h>
#include <hip/hip_bf16.h>

#define N_S     64
#define C_CH    128
#define L_SEQ   1600
#define H_HEADS 8
#define HD      16
#define SEG     50    // 32 segments * 50 = 1600
#define PADW    136   // weight LDS row pad (bf16 elems)
#define PADT    72    // x/y tile LDS row pad (bf16 elems)

typedef __attribute__((ext_vector_type(8))) short bf16x8;
typedef __attribute__((ext_vector_type(4))) float f32x4;

__device__ inline unsigned short f2bf(float f) {
  return __builtin_bit_cast(unsigned short, __float2bfloat16(f));
}
__device__ inline float bflo(unsigned int u) { return __builtin_bit_cast(float, u << 16); }
__device__ inline float bfhi(unsigned int u) { return __builtin_bit_cast(float, u & 0xffff0000u); }

// ---------------- K1: w2[n, c=16h+d, l] (bf16) = sum_c x[n,c,l]*Wa[16h+d][c] + ba ----------------
__global__ __launch_bounds__(256) void k_gemm1(const float* __restrict__ x,
                                               const float* __restrict__ Wa,
                                               const float* __restrict__ ba,
                                               unsigned short* __restrict__ w2) {
  __shared__ unsigned short was[128 * PADW];   // [o][c] rows
  __shared__ unsigned short xs[128 * PADT];    // [c][l] natural layout
  const int n = blockIdx.y;
  const int l0 = blockIdx.x * 64;
  const int t = threadIdx.x;
  const float* xn = x + (size_t)n * (C_CH * L_SEQ);

#pragma unroll
  for (int it = 0; it < 16; ++it) {
    int pos = it * 256 + t;
    int o = pos >> 5;
    int c4 = (pos & 31) << 2;
    float4 v = *reinterpret_cast<const float4*>(Wa + o * C_CH + c4);
    ushort4 u;
    u.x = f2bf(v.x); u.y = f2bf(v.y); u.z = f2bf(v.z); u.w = f2bf(v.w);
    *reinterpret_cast<ushort4*>(&was[o * PADW + c4]) = u;
  }
#pragma unroll
  for (int it = 0; it < 8; ++it) {
    int pos = it * 256 + t;
    int c = pos >> 4;
    int l4 = (pos & 15) << 2;
    float4 v = *reinterpret_cast<const float4*>(xn + (size_t)c * L_SEQ + l0 + l4);
    ushort4 u;
    u.x = f2bf(v.x); u.y = f2bf(v.y); u.z = f2bf(v.z); u.w = f2bf(v.w);
    *reinterpret_cast<ushort4*>(&xs[c * PADT + l4]) = u;
  }
  __syncthreads();

  const int wv = t >> 6;
  const int lane = t & 63;
  const int r16 = lane & 15;
  const int kg = lane >> 4;
  f32x4 acc[8];
#pragma unroll
  for (int ot = 0; ot < 8; ++ot) acc[ot] = (f32x4){0.f, 0.f, 0.f, 0.f};

#pragma unroll
  for (int ks = 0; ks < 4; ++ks) {
    bf16x8 a;
#pragma unroll
    for (int j = 0; j < 8; ++j)
      a[j] = (short)xs[(ks * 32 + kg * 8 + j) * PADT + wv * 16 + r16];
#pragma unroll
    for (int ot = 0; ot < 8; ++ot) {
      bf16x8 b = *reinterpret_cast<const bf16x8*>(&was[(ot * 16 + r16) * PADW + ks * 32 + kg * 8]);
      acc[ot] = __builtin_amdgcn_mfma_f32_16x16x32_bf16(a, b, acc[ot], 0, 0, 0);
    }
  }
#pragma unroll
  for (int ot = 0; ot < 8; ++ot) {
    float bav = ba[ot * 16 + r16];
    ushort4 u;
    u.x = f2bf(acc[ot][0] + bav);
    u.y = f2bf(acc[ot][1] + bav);
    u.z = f2bf(acc[ot][2] + bav);
    u.w = f2bf(acc[ot][3] + bav);
    size_t idx = (((size_t)n * H_HEADS + ot) * HD + r16) * L_SEQ + l0 + wv * 16 + kg * 4;
    *reinterpret_cast<ushort4*>(&w2[idx]) = u;
  }
}

// ---------------- K2: per-(n,h) scan pipeline; LDS transpose-sum, no shfl chains ----------------
__global__ __launch_bounds__(512) void k_scan(const unsigned short* __restrict__ w2,
                                              unsigned short* __restrict__ y2,
                                              const float* __restrict__ temp,
                                              const float* __restrict__ dbias) {
  __shared__ float tmp_l[L_SEQ];          // raw e = exp(tmp - M) (unnormalized)
  __shared__ float cbuf[32][10][17];      // chunk transpose buffer
  __shared__ float stot[32][17];
  __shared__ float pi_seg[32];
  __shared__ float red[16];
  const int nh = blockIdx.x;
  const int h = nh & 7;
  const int t = threadIdx.x;
  const int d = t & 15;
  const int seg = t >> 4;
  const int l0 = seg * SEG;
  const size_t base = ((size_t)nh * HD + d) * L_SEQ + l0;
  const float tscale = temp[h];
  const float db16 = 16.f * dbias[h];

  // contiguous 50-elem bf16 slice -> 25 packed dwords
  unsigned int vp[25];
#pragma unroll
  for (int ii = 0; ii < 25; ++ii)
    vp[ii] = *reinterpret_cast<const unsigned int*>(w2 + base + 2 * ii);

  // sweep 1a: per-segment sum of w^2 per channel
  float tot = 0.f;
#pragma unroll
  for (int ii = 0; ii < 25; ++ii) {
    float a = bflo(vp[ii]), b = bfhi(vp[ii]);
    tot += a * a + b * b;
  }
  stot[seg][d] = tot;
  __syncthreads();
  float off = 0.f;
#pragma unroll
  for (int s = 0; s < 32; ++s) { float q = stot[s][d]; if (s < seg) off += q; }

  // sweep 1b: cumsum of wsq -> c0 = wsq/denom; chunked LDS transpose-sum over d
  {
    float run = off;
    const int s2 = t / 10;        // 0..31 when t<320
    const int j2 = t - s2 * 10;
#pragma unroll
    for (int i0 = 0; i0 < SEG; i0 += 10) {
      float c0[10];
#pragma unroll
      for (int j = 0; j < 10; ++j) {
        int i = i0 + j;
        float v = (i & 1) ? bfhi(vp[i >> 1]) : bflo(vp[i >> 1]);
        float wsq = v * v;
        run += wsq;
        c0[j] = __fdividef(wsq, fmaxf(run, 1e-12f));
      }
      if (i0) __syncthreads();    // previous chunk's readers done
#pragma unroll
      for (int j = 0; j < 10; ++j) cbuf[seg][j][d] = c0[j];
      __syncthreads();
      if (t < 320) {
        float a = 0.f;
#pragma unroll
        for (int dd = 0; dd < 16; ++dd) a += cbuf[s2][j2][dd];
        tmp_l[s2 * SEG + i0 + j2] = (a + db16) * tscale;
      }
    }
  }
  __syncthreads();

  // softmax over tmp_l: compute M, then e (unnormalized), and S
  float m = -3.0e38f;
  for (int l = t; l < L_SEQ; l += 512) m = fmaxf(m, tmp_l[l]);
#pragma unroll
  for (int mask = 32; mask; mask >>= 1) m = fmaxf(m, __shfl_xor(m, mask));
  const int wid = t >> 6;
  if ((t & 63) == 0) red[wid] = m;
  __syncthreads();
  float M = red[0];
#pragma unroll
  for (int i2 = 1; i2 < 8; ++i2) M = fmaxf(M, red[i2]);
  float s = 0.f;
  for (int l = t; l < L_SEQ; l += 512) {
    float e = __expf(tmp_l[l] - M);
    tmp_l[l] = e;
    s += e;
  }
#pragma unroll
  for (int mask = 32; mask; mask >>= 1) s += __shfl_xor(s, mask);
  if ((t & 63) == 0) red[8 + wid] = s;
  __syncthreads();
  float S = 0.f;
#pragma unroll
  for (int i2 = 0; i2 < 8; ++i2) S += red[8 + i2];
  const float ninvS = -1.0f / S;
  const float epsS = 1e-8f * S;

  // sweep 2a: per-segment totals of wsq*e (per d) and e (unnormalized)
  float wp_tot = 0.f, pi_tot = 0.f;
#pragma unroll
  for (int ii = 0; ii < 25; ++ii) {
    float a = bflo(vp[ii]), b = bfhi(vp[ii]);
    float e0 = tmp_l[l0 + 2 * ii];
    float e1 = tmp_l[l0 + 2 * ii + 1];
    wp_tot += a * a * e0 + b * b * e1;
    pi_tot += e0 + e1;
  }
  stot[seg][d] = wp_tot;
  if (d == 0) pi_seg[seg] = pi_tot;
  __syncthreads();
  float wp_off = 0.f, pi_off = 0.f;
#pragma unroll
  for (int s2 = 0; s2 < 32; ++s2) {
    float vw = stot[s2][d];
    float vq = pi_seg[s2];
    if (s2 < seg) { wp_off += vw; pi_off += vq; }
  }

  // sweep 2b: unnormalized running cumsums -> y = (w*e*attn)*(-invS)
  {
    float run_wp = wp_off, run_pi = pi_off;
#pragma unroll
    for (int ii = 0; ii < 25; ++ii) {
      float v0 = bflo(vp[ii]), v1 = bfhi(vp[ii]);
      float e0 = tmp_l[l0 + 2 * ii];
      run_pi += e0;
      run_wp += v0 * v0 * e0;
      float dn0 = run_pi + epsS;
      float y0 = (v0 * e0) * __fdividef(dn0, dn0 + run_wp) * ninvS;
      float e1 = tmp_l[l0 + 2 * ii + 1];
      run_pi += e1;
      run_wp += v1 * v1 * e1;
      float dn1 = run_pi + epsS;
      float y1 = (v1 * e1) * __fdividef(dn1, dn1 + run_wp) * ninvS;
      vp[ii] = (unsigned int)f2bf(y0) | ((unsigned int)f2bf(y1) << 16);
    }
  }
#pragma unroll
  for (int ii = 0; ii < 25; ++ii)
    *reinterpret_cast<unsigned int*>(y2 + base + 2 * ii) = vp[ii];
}

// ---------------- K3: out = relu(Wp . y + bp + x)  (bf16 MFMA, y2 d-major) ----------------
__global__ __launch_bounds__(256) void k_gemm2(const unsigned short* __restrict__ y2,
                                               const float* __restrict__ Wp,
                                               const float* __restrict__ bp,
                                               const float* __restrict__ x,
                                               float* __restrict__ out) {
  __shared__ unsigned short wps[128 * PADW];   // [o][c] rows
  __shared__ unsigned short ys[128 * PADT];    // [c][l] natural layout
  const int n = blockIdx.y;
  const int l0 = blockIdx.x * 64;
  const int t = threadIdx.x;

#pragma unroll
  for (int it = 0; it < 16; ++it) {
    int pos = it * 256 + t;
    int o = pos >> 5;
    int c4 = (pos & 31) << 2;
    float4 v = *reinterpret_cast<const float4*>(Wp + o * C_CH + c4);
    ushort4 u;
    u.x = f2bf(v.x); u.y = f2bf(v.y); u.z = f2bf(v.z); u.w = f2bf(v.w);
    *reinterpret_cast<ushort4*>(&wps[o * PADW + c4]) = u;
  }
#pragma unroll
  for (int it = 0; it < 4; ++it) {
    int pos = it * 256 + t;          // 0..1023
    int c = pos >> 3;
    int l8 = (pos & 7) << 3;
    uint4 v = *reinterpret_cast<const uint4*>(y2 + ((size_t)n * C_CH + c) * L_SEQ + l0 + l8);
    *reinterpret_cast<uint4*>(&ys[c * PADT + l8]) = v;
  }
  __syncthreads();

  const int wv = t >> 6;
  const int lane = t & 63;
  const int r16 = lane & 15;
  const int kg = lane >> 4;
  f32x4 acc[8];
#pragma unroll
  for (int ot = 0; ot < 8; ++ot) acc[ot] = (f32x4){0.f, 0.f, 0.f, 0.f};

#pragma unroll
  for (int ks = 0; ks < 4; ++ks) {
    bf16x8 b;
#pragma unroll
    for (int j = 0; j < 8; ++j)
      b[j] = (short)ys[(ks * 32 + kg * 8 + j) * PADT + wv * 16 + r16];
#pragma unroll
    for (int ot = 0; ot < 8; ++ot) {
      bf16x8 a = *reinterpret_cast<const bf16x8*>(&wps[(ot * 16 + r16) * PADW + ks * 32 + kg * 8]);
      acc[ot] = __builtin_amdgcn_mfma_f32_16x16x32_bf16(a, b, acc[ot], 0, 0, 0);
    }
  }
  const int gl = l0 + wv * 16 + r16;
#pragma unroll
  for (int ot = 0; ot < 8; ++ot) {
#pragma unroll
    for (int i = 0; i < 4; ++i) {
      int o = ot * 16 + kg * 4 + i;
      size_t idx = (size_t)n * (C_CH * L_SEQ) + (size_t)o * L_SEQ + gl;
      float r = acc[ot][i] + bp[o] + x[idx];
      out[idx] = fmaxf(r, 0.f);
    }
  }
}

extern "C" void kernel_launch(void* const* d_in, const int* in_sizes, int n_in,
                              void* d_out, int out_size, void* d_ws, size_t ws_size,
                              hipStream_t stream) {
  const float* x     = (const float*)d_in[0];
  const float* Wa    = (const float*)d_in[1];
  const float* ba    = (const float*)d_in[2];
  const float* Wp    = (const float*)d_in[3];
  const float* bp    = (const float*)d_in[4];
  const float* temp  = (const float*)d_in[5];
  const float* dbias = (const float*)d_in[6];
  float* out = (float*)d_out;

  unsigned short* w2 = (unsigned short*)d_ws;                       // 26.2 MB
  unsigned short* y2 = w2 + (size_t)N_S * H_HEADS * L_SEQ * HD;     // 26.2 MB

  k_gemm1<<<dim3(L_SEQ / 64, N_S), 256, 0, stream>>>(x, Wa, ba, w2);
  k_scan<<<N_S * H_HEADS, 512, 0, stream>>>(w2, y2, temp, dbias);
  k_gemm2<<<dim3(L_SEQ / 64, N_S), 256, 0, stream>>>(y2, Wp, bp, x, out);
}